// Round 2
// baseline (8174.636 us; speedup 1.0000x reference)
//
#include <hip/hip_runtime.h>

#define NPTS 2048
#define KNN_K 20
#define BATCH 16

constexpr float EPSV   = 1e-5f;
constexpr float SLOPEV = 0.2f;

__device__ __forceinline__ float dot4(float4 a, float4 b, float acc) {
  acc = fmaf(a.x, b.x, acc);
  acc = fmaf(a.y, b.y, acc);
  acc = fmaf(a.z, b.z, acc);
  acc = fmaf(a.w, b.w, acc);
  return acc;
}

// ---------------- squared norms: one thread per (b,n) ----------------
template<int C>
__global__ void sq_kernel(const float* __restrict__ XT, float* __restrict__ SQ) {
  int i = blockIdx.x * 256 + threadIdx.x;          // i = b*NPTS + n
  const float* r = XT + (long)i * C;
  float s = 0.f;
  if constexpr (C % 4 == 0) {
    const float4* r4 = (const float4*)r;
    #pragma unroll
    for (int c = 0; c < C / 4; ++c) { float4 v = r4[c]; s = dot4(v, v, s); }
  } else {
    #pragma unroll
    for (int c = 0; c < C; ++c) s = fmaf(r[c], r[c], s);
  }
  SQ[i] = s;
}

// ---------------- KNN: 2 threads per row (halves of m-range) ----------------
// pd = 2*dot(xn,xm) - sq[n] - sq[m]; top-20 by value desc, ties -> lower index
template<int C>
__global__ __launch_bounds__(256, 1) void knn_kernel(const float* __restrict__ XT,
                                                     const float* __restrict__ SQ,
                                                     int* __restrict__ IDX) {
  __shared__ float ld[256][KNN_K];
  __shared__ int   li[256][KNN_K];
  int t    = threadIdx.x;
  int gr   = blockIdx.x * 128 + (t >> 1);          // global row = b*NPTS+n
  int b    = gr >> 11;
  int half = t & 1;

  float sqn = SQ[gr];
  const float* xb  = XT + ((long)b << 11) * C;
  const float* sqb = SQ + ((long)b << 11);

  float topd[KNN_K]; int topi[KNN_K];
  #pragma unroll
  for (int j = 0; j < KNN_K; ++j) { topd[j] = -3e38f; topi[j] = 0; }

  if constexpr (C % 4 == 0) {
    float4 xn4[C / 4];
    const float4* xr = (const float4*)(XT + (long)gr * C);
    #pragma unroll
    for (int c = 0; c < C / 4; ++c) xn4[c] = xr[c];

    int m0 = half << 10;
    for (int mm = 0; mm < 1024; ++mm) {
      int m = m0 + mm;
      const float4* xm4 = (const float4*)(xb + (long)m * C);
      float dot = 0.f;
      #pragma unroll
      for (int c = 0; c < C / 4; ++c) dot = dot4(xn4[c], xm4[c], dot);
      float pd = fmaf(2.f, dot, -sqn) - sqb[m];
      if (pd > topd[KNN_K - 1]) {
        float d = pd; int ii = m;
        #pragma unroll
        for (int j = 0; j < KNN_K; ++j) {
          bool sw = d > topd[j];
          float td = sw ? d : topd[j]; float dd = sw ? topd[j] : d;
          int   ti = sw ? ii : topi[j]; int  di = sw ? topi[j] : ii;
          topd[j] = td; d = dd; topi[j] = ti; ii = di;
        }
      }
    }
  } else {
    float xn[C];
    const float* xr = XT + (long)gr * C;
    #pragma unroll
    for (int c = 0; c < C; ++c) xn[c] = xr[c];

    int m0 = half << 10;
    for (int mm = 0; mm < 1024; ++mm) {
      int m = m0 + mm;
      const float* xm = xb + (long)m * C;
      float dot = 0.f;
      #pragma unroll
      for (int c = 0; c < C; ++c) dot = fmaf(xn[c], xm[c], dot);
      float pd = fmaf(2.f, dot, -sqn) - sqb[m];
      if (pd > topd[KNN_K - 1]) {
        float d = pd; int ii = m;
        #pragma unroll
        for (int j = 0; j < KNN_K; ++j) {
          bool sw = d > topd[j];
          float td = sw ? d : topd[j]; float dd = sw ? topd[j] : d;
          int   ti = sw ? ii : topi[j]; int  di = sw ? topi[j] : ii;
          topd[j] = td; d = dd; topi[j] = ti; ii = di;
        }
      }
    }
  }

  #pragma unroll
  for (int j = 0; j < KNN_K; ++j) { ld[t][j] = topd[j]; li[t][j] = topi[j]; }
  __syncthreads();

  if (t < 128) {
    int a = 2 * t, c2 = 2 * t + 1;
    int grow = blockIdx.x * 128 + t;
    int* dst = IDX + (long)grow * KNN_K;
    int ia = 0, ib = 0;
    for (int j = 0; j < KNN_K; ++j) {
      float da = ld[a][ia], db = ld[c2][ib];
      bool ta = (da >= db);                        // tie -> low half (lower m) first
      dst[j] = ta ? li[a][ia] : li[c2][ib];
      ia += ta ? 1 : 0; ib += ta ? 0 : 1;
    }
  }
}

// ---------------- edge conv + BN + LeakyReLU + max over k ----------------
// z_k = W1p·x_nb(k) + (W2p - W1p)·x_n ; y = max_k act(scale*z_k + shift)
template<int O, int C>
__global__ __launch_bounds__(256, 2) void conv_kernel(const float* __restrict__ XTin,
                                                      const int* __restrict__ IDX,
                                                      const float* __restrict__ W,
                                                      const float* __restrict__ gg,
                                                      const float* __restrict__ bbias,
                                                      const float* __restrict__ mmean,
                                                      const float* __restrict__ vvar,
                                                      float* __restrict__ XTout) {
  constexpr int G   = 256 / O;        // threads per o
  constexpr int KPG = KNN_K / G;      // k's per thread
  __shared__ float cols[KNN_K + 1][C];

  int bid = blockIdx.x;               // = b*NPTS + n
  int b = bid >> 11, n = bid & 2047;
  int t = threadIdx.x;
  long rowbase = ((long)b << 11);
  const int* idxp = IDX + (long)bid * KNN_K;

  if constexpr (C % 4 == 0) {
    constexpr int C4 = C / 4;
    for (int e = t; e < (KNN_K + 1) * C4; e += 256) {
      int col = e / C4, c4 = e - col * C4;
      int j = (col == 0) ? n : idxp[col - 1];
      float4 v = *(const float4*)(XTin + (rowbase + j) * C + c4 * 4);
      *(float4*)&cols[col][c4 * 4] = v;
    }
  } else {
    for (int e = t; e < (KNN_K + 1) * C; e += 256) {
      int col = e / C, c = e - col * C;
      int j = (col == 0) ? n : idxp[col - 1];
      cols[col][c] = XTin[(rowbase + j) * C + c];
    }
  }
  __syncthreads();

  int o = t / G, kg = t - o * G;
  const float* wrow = W + o * (2 * C);

  float acc[KPG];
  #pragma unroll
  for (int q = 0; q < KPG; ++q) acc[q] = 0.f;
  float s1 = 0.f, u2 = 0.f;

  if constexpr (C % 4 == 0) {
    for (int c4 = 0; c4 < C / 4; ++c4) {
      float4 w1 = *(const float4*)(wrow + c4 * 4);
      float4 w2 = *(const float4*)(wrow + C + c4 * 4);
      float4 xn = *(const float4*)&cols[0][c4 * 4];
      s1 = dot4(w1, xn, s1);
      u2 = dot4(w2, xn, u2);
      #pragma unroll
      for (int q = 0; q < KPG; ++q) {
        int k = kg * KPG + q;
        float4 xv = *(const float4*)&cols[1 + k][c4 * 4];
        acc[q] = dot4(w1, xv, acc[q]);
      }
    }
  } else {
    #pragma unroll
    for (int c = 0; c < C; ++c) {
      float w1 = wrow[c];
      float w2 = wrow[C + c];
      float xn = cols[0][c];
      s1 = fmaf(w1, xn, s1);
      u2 = fmaf(w2, xn, u2);
      #pragma unroll
      for (int q = 0; q < KPG; ++q) {
        int k = kg * KPG + q;
        acc[q] = fmaf(w1, cols[1 + k][c], acc[q]);
      }
    }
  }

  float sc = gg[o] / sqrtf(vvar[o] + EPSV);
  float sh = bbias[o] - mmean[o] * sc;
  float vmax = -3e38f;
  #pragma unroll
  for (int q = 0; q < KPG; ++q) {
    float z = acc[q] - s1 + u2;
    float y = fmaf(sc, z, sh);
    y = (y >= 0.f) ? y : SLOPEV * y;
    vmax = fmaxf(vmax, y);
  }
  #pragma unroll
  for (int off = 1; off < G; off <<= 1)
    vmax = fmaxf(vmax, __shfl_xor(vmax, off, 64));
  if (kg == 0) XTout[(rowbase + n) * O + o] = vmax;
}

// ---------------- final: y[b,o] = max_n act(s*W5·cat[b,:,n] + t) ----------------
__global__ __launch_bounds__(256, 2) void final_kernel(const float* __restrict__ X1,
                                                       const float* __restrict__ X2,
                                                       const float* __restrict__ X3,
                                                       const float* __restrict__ X4,
                                                       const float* __restrict__ W5,
                                                       const float* __restrict__ g5,
                                                       const float* __restrict__ b5,
                                                       const float* __restrict__ m5,
                                                       const float* __restrict__ v5,
                                                       float* __restrict__ RED) {
  __shared__ float tile[16][512];
  int bid = blockIdx.x;                 // b*128 + chunk
  int b = bid >> 7, chunk = bid & 127;
  int n0 = chunk * 16;
  int t = threadIdx.x;

  for (int e = t; e < 16 * 128; e += 256) {
    int nn = e >> 7, c4 = e & 127;
    int c = c4 * 4;
    long row = ((long)b << 11) + n0 + nn;
    float4 v;
    if      (c < 64)  v = *(const float4*)(X1 + row * 64  + c);
    else if (c < 128) v = *(const float4*)(X2 + row * 64  + (c - 64));
    else if (c < 256) v = *(const float4*)(X3 + row * 128 + (c - 128));
    else              v = *(const float4*)(X4 + row * 256 + (c - 256));
    *(float4*)&tile[nn][c] = v;
  }
  __syncthreads();

  int o = t;
  const float* wrow = W5 + o * 512;
  float acc[16];
  #pragma unroll
  for (int q = 0; q < 16; ++q) acc[q] = 0.f;
  for (int c4 = 0; c4 < 128; ++c4) {
    float4 w = *(const float4*)(wrow + c4 * 4);
    #pragma unroll
    for (int q = 0; q < 16; ++q) {
      float4 xv = *(const float4*)&tile[q][c4 * 4];
      acc[q] = dot4(w, xv, acc[q]);
    }
  }
  float sc = g5[o] / sqrtf(v5[o] + EPSV);
  float sh = b5[o] - m5[o] * sc;
  float vmax = -3e38f;
  #pragma unroll
  for (int q = 0; q < 16; ++q) {
    float y = fmaf(sc, acc[q], sh);
    y = (y >= 0.f) ? y : SLOPEV * y;
    vmax = fmaxf(vmax, y);
  }
  RED[((long)b * 256 + o) * 128 + chunk] = vmax;
}

__global__ void reduce_kernel(const float* __restrict__ RED, float* __restrict__ out) {
  int i = blockIdx.x * 256 + threadIdx.x;   // 4096 outputs
  const float* r = RED + (long)i * 128;
  float v = r[0];
  for (int j = 1; j < 128; ++j) v = fmaxf(v, r[j]);
  out[i] = v;
}

extern "C" void kernel_launch(void* const* d_in, const int* in_sizes, int n_in,
                              void* d_out, int out_size, void* d_ws, size_t ws_size,
                              hipStream_t stream) {
  (void)in_sizes; (void)n_in; (void)out_size; (void)ws_size;
  const float* pc = (const float*)d_in[0];                 // (16,2048,3) row-major = XT0
  const float* W1 = (const float*)d_in[1];
  const float* g1 = (const float*)d_in[2];
  const float* b1 = (const float*)d_in[3];
  const float* m1 = (const float*)d_in[4];
  const float* v1 = (const float*)d_in[5];
  const float* W2 = (const float*)d_in[6];
  const float* g2 = (const float*)d_in[7];
  const float* b2 = (const float*)d_in[8];
  const float* m2 = (const float*)d_in[9];
  const float* v2 = (const float*)d_in[10];
  const float* W3 = (const float*)d_in[11];
  const float* g3 = (const float*)d_in[12];
  const float* b3 = (const float*)d_in[13];
  const float* m3 = (const float*)d_in[14];
  const float* v3 = (const float*)d_in[15];
  const float* W4 = (const float*)d_in[16];
  const float* g4 = (const float*)d_in[17];
  const float* b4 = (const float*)d_in[18];
  const float* m4 = (const float*)d_in[19];
  const float* v4 = (const float*)d_in[20];
  const float* W5 = (const float*)d_in[21];
  const float* g5 = (const float*)d_in[22];
  const float* b5 = (const float*)d_in[23];
  const float* m5 = (const float*)d_in[24];
  const float* v5 = (const float*)d_in[25];
  float* out = (float*)d_out;

  // workspace carving (floats), all row-major [b][n][C]
  float* XT1 = (float*)d_ws;            // 16*2048*64
  float* XT2 = XT1 + 2097152;           // 16*2048*64
  float* XT3 = XT2 + 2097152;           // 16*2048*128
  float* XT4 = XT3 + 4194304;           // 16*2048*256
  float* SQ  = XT4 + 8388608;           // 16*2048
  float* RED = SQ  + 32768;             // 16*256*128
  int*   IDX = (int*)(RED + 524288);    // 16*2048*20

  const int BN = BATCH * NPTS;          // 32768

  // stage 1 (C=3 from pc)
  sq_kernel<3><<<BN / 256, 256, 0, stream>>>(pc, SQ);
  knn_kernel<3><<<BN / 128, 256, 0, stream>>>(pc, SQ, IDX);
  conv_kernel<64, 3><<<BN, 256, 0, stream>>>(pc, IDX, W1, g1, b1, m1, v1, XT1);
  // stage 2
  sq_kernel<64><<<BN / 256, 256, 0, stream>>>(XT1, SQ);
  knn_kernel<64><<<BN / 128, 256, 0, stream>>>(XT1, SQ, IDX);
  conv_kernel<64, 64><<<BN, 256, 0, stream>>>(XT1, IDX, W2, g2, b2, m2, v2, XT2);
  // stage 3
  sq_kernel<64><<<BN / 256, 256, 0, stream>>>(XT2, SQ);
  knn_kernel<64><<<BN / 128, 256, 0, stream>>>(XT2, SQ, IDX);
  conv_kernel<128, 64><<<BN, 256, 0, stream>>>(XT2, IDX, W3, g3, b3, m3, v3, XT3);
  // stage 4
  sq_kernel<128><<<BN / 256, 256, 0, stream>>>(XT3, SQ);
  knn_kernel<128><<<BN / 128, 256, 0, stream>>>(XT3, SQ, IDX);
  conv_kernel<256, 128><<<BN, 256, 0, stream>>>(XT3, IDX, W4, g4, b4, m4, v4, XT4);
  // final
  final_kernel<<<BATCH * 128, 256, 0, stream>>>(XT1, XT2, XT3, XT4, W5, g5, b5, m5, v5, RED);
  reduce_kernel<<<BATCH, 256, 0, stream>>>(RED, out);
}